// Round 7
// baseline (908.012 us; speedup 1.0000x reference)
//
#include <hip/hip_runtime.h>
#include <hip/hip_cooperative_groups.h>

namespace cg = cooperative_groups;

#define NN 40000
#define DD 128
#define EE 640000
#define SLOPE 0.01f
#define GRID 768
#define TPB 256
#define NTHREADS (GRID * TPB)

typedef __attribute__((ext_vector_type(8))) short  short8;   // 8 x bf16
typedef __attribute__((ext_vector_type(8))) unsigned short ushort8;
typedef __attribute__((ext_vector_type(4))) float  floatx4;  // MFMA acc

__device__ __forceinline__ float leaky1(float v) { return v >= 0.f ? v : v * SLOPE; }

__device__ __forceinline__ unsigned short f2bf(float f) {
    unsigned int u = __float_as_uint(f);
    u += 0x7fffu + ((u >> 16) & 1u);       // RNE
    return (unsigned short)(u >> 16);
}

// ===========================================================================
// PATH A: single cooperative mega-kernel (17.6 KB LDS, 3 blk/CU, grid 768)
//  P0: deg=0, pack weights, x->bf16
//  P1: edge histogram + node_pre MFMA (delta via shfl_xor, u scattered)
//  P2: scan_up (40 blocks x 1000)
//  P3: scan finish -> off, cur
//  P4: CSR scatter
//  P5: pull-mode gather -> aggrb
//  P6: node_out MFMA -> out (scattered epilogue)
// ===========================================================================
__global__ __launch_bounds__(TPB, 3) void k_mega(
    const float* __restrict__ x, const float* __restrict__ pos,
    const int* __restrict__ ei,
    const float* __restrict__ Wh1, const float* __restrict__ bh1,
    const float* __restrict__ Wh2, const float* __restrict__ bh2,
    const float* __restrict__ Wf1, const float* __restrict__ bf1,
    const float* __restrict__ Wg1, const float* __restrict__ bg1,
    const float* __restrict__ Wg2, const float* __restrict__ bg2,
    float* __restrict__ out,
    unsigned short* __restrict__ xb, unsigned short* __restrict__ ub,
    unsigned short* __restrict__ aggrb, unsigned short* __restrict__ pk,
    float* __restrict__ delta, int* __restrict__ deg, int* __restrict__ off,
    int* __restrict__ cur, int* __restrict__ esrc, int* __restrict__ bsum)
{
    cg::grid_group gg = cg::this_grid();

    __shared__ unsigned short ul[64 * 136];   // bf16 tile (g in P6)
    __shared__ int            sscan[44];

    const int t   = threadIdx.x;
    const int b   = blockIdx.x;
    const int gid = b * TPB + t;
    const int w   = t >> 6, l = t & 63;
    const int lm  = l & 15, q = l >> 4;

    // ================= P0 ===================================================
    if (gid < NN) deg[gid] = 0;

    if (gid < 8192) {
        const int mat = gid >> 11;
        const int rem = gid & 2047;
        const int ct  = rem >> 8;
        const int kc  = (rem >> 6) & 3;
        const int ll  = rem & 63;
        const float* W = (mat == 0) ? Wh1 : (mat == 1) ? (Wf1 + 3 * DD)
                       : (mat == 2) ? Wg1 : Wg2;
        const int nn = ct * 16 + (ll & 15);
        const int k0 = kc * 32 + (ll >> 4) * 8;
        ushort8 v;
        #pragma unroll
        for (int j = 0; j < 8; ++j) v[j] = f2bf(W[(size_t)(k0 + j) * DD + nn]);
        *(ushort8*)(pk + (size_t)gid * 8) = v;
    }

    for (int i = gid; i < NN * DD / 16; i += NTHREADS) {
        const size_t base = (size_t)i * 16;
        ushort8 o0, o1;
        #pragma unroll
        for (int qq = 0; qq < 2; ++qq) {
            #pragma unroll
            for (int p = 0; p < 2; ++p) {
                const float4 v = *(const float4*)(x + base + qq * 8 + p * 4);
                ushort8& o = qq ? o1 : o0;
                o[p * 4 + 0] = f2bf(v.x);
                o[p * 4 + 1] = f2bf(v.y);
                o[p * 4 + 2] = f2bf(v.z);
                o[p * 4 + 3] = f2bf(v.w);
            }
        }
        *(ushort8*)(xb + base)     = o0;
        *(ushort8*)(xb + base + 8) = o1;
    }
    gg.sync();

    // ================= P1: histogram + node_pre =============================
    for (int e = gid; e < EE; e += NTHREADS)
        atomicAdd(&deg[ei[EE + e]], 1);

    for (int tile = b; tile < NN / 64; tile += GRID) {
        const int row0 = tile * 64 + w * 16;
        const unsigned short* pkh = pk;            // Wh1
        const unsigned short* pkf = pk + 16384;    // Wf1[3:]

        floatx4 hacc[8], facc[8];
        #pragma unroll
        for (int ct = 0; ct < 8; ++ct) { hacc[ct] = 0.f; facc[ct] = 0.f; }

        #pragma unroll
        for (int kc = 0; kc < 4; ++kc) {
            const short8 a = *(const short8*)(xb + (size_t)(row0 + lm) * DD + kc * 32 + q * 8);
            #pragma unroll
            for (int ct = 0; ct < 8; ++ct) {
                const short8 bh = *(const short8*)(pkh + (size_t)((ct * 4 + kc) * 64 + l) * 8);
                const short8 bf = *(const short8*)(pkf + (size_t)((ct * 4 + kc) * 64 + l) * 8);
                hacc[ct] = __builtin_amdgcn_mfma_f32_16x16x32_bf16(a, bh, hacc[ct], 0, 0, 0);
                facc[ct] = __builtin_amdgcn_mfma_f32_16x16x32_bf16(a, bf, facc[ct], 0, 0, 0);
            }
        }

        float px[4][3];
        #pragma unroll
        for (int r = 0; r < 4; ++r) {
            const int rr = row0 + q * 4 + r;
            px[r][0] = pos[rr * 3 + 0];
            px[r][1] = pos[rr * 3 + 1];
            px[r][2] = pos[rr * 3 + 2];
        }

        // delta partials + u scattered store. D layout: row=q*4+r, col=ct*16+lm.
        float p[4][3] = {};
        #pragma unroll
        for (int ct = 0; ct < 8; ++ct) {
            const int col = ct * 16 + lm;
            const float b1 = bh1[col];
            const float bfv = bf1[col];
            const float w0 = Wf1[0 * DD + col];
            const float w1 = Wf1[1 * DD + col];
            const float w2 = Wf1[2 * DD + col];
            const float wh20 = Wh2[col * 3 + 0];
            const float wh21 = Wh2[col * 3 + 1];
            const float wh22 = Wh2[col * 3 + 2];
            #pragma unroll
            for (int r = 0; r < 4; ++r) {
                const float uv = facc[ct][r] + bfv
                               + px[r][0] * w0 + px[r][1] * w1 + px[r][2] * w2;
                ub[(size_t)(row0 + q * 4 + r) * DD + col] = f2bf(uv);
                const float hv = leaky1(hacc[ct][r] + b1);
                p[r][0] += hv * wh20;
                p[r][1] += hv * wh21;
                p[r][2] += hv * wh22;
            }
        }
        // reduce over the 16 lanes of this quad (lane bits 0..3)
        #pragma unroll
        for (int m = 1; m < 16; m <<= 1) {
            #pragma unroll
            for (int r = 0; r < 4; ++r) {
                #pragma unroll
                for (int k = 0; k < 3; ++k)
                    p[r][k] += __shfl_xor(p[r][k], m);
            }
        }
        if (lm < 12) {
            const int r = lm >> 2;        // wrong mapping? no: use lm/3 grouping
        }
        // 12 writes: lm in [0,12): r = lm/3, k = lm%3
        if (lm < 12) {
            const int r = lm / 3, k = lm - 3 * (lm / 3);
            delta[(size_t)(row0 + q * 4 + r) * 3 + k] = tanhf(p[r][k] + bh2[k]);
        }
    }
    gg.sync();

    // ================= P2: scan_up (40 blocks x 1000) =======================
    if (b < 40) {
        const int base = b * 1000;
        int v[4], s = 0;
        #pragma unroll
        for (int k = 0; k < 4; ++k) {
            const int i = t * 4 + k;
            v[k] = (i < 1000) ? deg[base + i] : 0;
            s += v[k];
        }
        int incl = s;
        #pragma unroll
        for (int d = 1; d < 64; d <<= 1) {
            const int o = __shfl_up(incl, d);
            if (l >= d) incl += o;
        }
        if (l == 63) sscan[w] = incl;
        __syncthreads();
        int wbase = 0;
        for (int k = 0; k < w; ++k) wbase += sscan[k];
        int run = wbase + incl - s;
        #pragma unroll
        for (int k = 0; k < 4; ++k) {
            const int i = t * 4 + k;
            if (i < 1000) { off[base + i] = run; run += v[k]; }
        }
        if (t == 0) {
            int tot = 0;
            #pragma unroll
            for (int k = 0; k < 4; ++k) tot += sscan[k];
            bsum[b] = tot;
        }
    }
    gg.sync();

    // ================= P3: scan finish ======================================
    if (t < 40) sscan[t] = bsum[t];
    __syncthreads();
    for (int i = gid; i < NN; i += NTHREADS) {
        const int chunk = i / 1000;
        int basepfx = 0;
        for (int k = 0; k < chunk; ++k) basepfx += sscan[k];
        const int o = off[i] + basepfx;
        off[i] = o;
        cur[i] = o;
    }
    if (gid == 0) off[NN] = EE;
    gg.sync();

    // ================= P4: CSR scatter ======================================
    for (int e = gid; e < EE; e += NTHREADS) {
        const int src = ei[e];
        const int dst = ei[EE + e];
        const int p2 = atomicAdd(&cur[dst], 1);
        esrc[p2] = src;
    }
    gg.sync();

    // ================= P5: gather ===========================================
    for (int quad = b; quad < NN / 4; quad += GRID) {
        const int n  = quad * 4 + w;
        const int c2 = l * 2;

        const float2 w0 = *(const float2*)(Wf1 + 0 * DD + c2);
        const float2 w1 = *(const float2*)(Wf1 + 1 * DD + c2);
        const float2 w2 = *(const float2*)(Wf1 + 2 * DD + c2);

        const float q0 = delta[n * 3 + 0] - pos[n * 3 + 0];
        const float q1 = delta[n * 3 + 1] - pos[n * 3 + 1];
        const float q2 = delta[n * 3 + 2] - pos[n * 3 + 2];

        const float v0 = q0 * w0.x + q1 * w1.x + q2 * w2.x;
        const float v1 = q0 * w0.y + q1 * w1.y + q2 * w2.y;

        float a0 = 0.f, a1 = 0.f, b0 = 0.f, b1 = 0.f;
        const int beg = off[n], end = off[n + 1];

#define EDGE_ACC(U, A0, A1)                                            \
        {                                                              \
            const float e0 = __uint_as_float((U) << 16) + v0;          \
            const float e1 = __uint_as_float((U) & 0xffff0000u) + v1;  \
            A0 += leaky1(e0);                                          \
            A1 += leaky1(e1);                                          \
        }

        int j = beg;
        for (; j + 3 < end; j += 4) {
            const int s0 = esrc[j];
            const int s1 = esrc[j + 1];
            const int s2 = esrc[j + 2];
            const int s3 = esrc[j + 3];
            const unsigned int u0 = *(const unsigned int*)(ub + (size_t)s0 * DD + c2);
            const unsigned int u1 = *(const unsigned int*)(ub + (size_t)s1 * DD + c2);
            const unsigned int u2 = *(const unsigned int*)(ub + (size_t)s2 * DD + c2);
            const unsigned int u3 = *(const unsigned int*)(ub + (size_t)s3 * DD + c2);
            EDGE_ACC(u0, a0, a1)
            EDGE_ACC(u1, b0, b1)
            EDGE_ACC(u2, a0, a1)
            EDGE_ACC(u3, b0, b1)
        }
        for (; j < end; ++j) {
            const int s0 = esrc[j];
            const unsigned int u0 = *(const unsigned int*)(ub + (size_t)s0 * DD + c2);
            EDGE_ACC(u0, a0, a1)
        }
#undef EDGE_ACC

        a0 += b0; a1 += b1;
        const unsigned int st = ((unsigned int)f2bf(a1) << 16) | (unsigned int)f2bf(a0);
        *(unsigned int*)(aggrb + (size_t)n * DD + c2) = st;
    }
    gg.sync();

    // ================= P6: node_out MFMA ====================================
    for (int tile = b; tile < NN / 64; tile += GRID) {
        const int rowb = tile * 64;
        const int row0 = rowb + w * 16;
        const unsigned short* pkg1 = pk + 32768;   // Wg1
        const unsigned short* pkg2 = pk + 49152;   // Wg2

        floatx4 gacc[8];
        #pragma unroll
        for (int ct = 0; ct < 8; ++ct) gacc[ct] = 0.f;

        #pragma unroll
        for (int kc = 0; kc < 4; ++kc) {
            const short8 a = *(const short8*)(aggrb + (size_t)(row0 + lm) * DD + kc * 32 + q * 8);
            #pragma unroll
            for (int ct = 0; ct < 8; ++ct) {
                const short8 bb = *(const short8*)(pkg1 + (size_t)((ct * 4 + kc) * 64 + l) * 8);
                gacc[ct] = __builtin_amdgcn_mfma_f32_16x16x32_bf16(a, bb, gacc[ct], 0, 0, 0);
            }
        }

        #pragma unroll
        for (int ct = 0; ct < 8; ++ct) {
            const int col = ct * 16 + lm;
            const float b1 = bg1[col];
            #pragma unroll
            for (int r = 0; r < 4; ++r)
                ul[(w * 16 + q * 4 + r) * 136 + col] = f2bf(leaky1(gacc[ct][r] + b1));
        }
        __syncthreads();

        floatx4 oacc[8];
        #pragma unroll
        for (int ct = 0; ct < 8; ++ct) oacc[ct] = 0.f;

        #pragma unroll
        for (int kc = 0; kc < 4; ++kc) {
            const short8 a = *(const short8*)(ul + (size_t)(w * 16 + lm) * 136 + kc * 32 + q * 8);
            #pragma unroll
            for (int ct = 0; ct < 8; ++ct) {
                const short8 bb = *(const short8*)(pkg2 + (size_t)((ct * 4 + kc) * 64 + l) * 8);
                oacc[ct] = __builtin_amdgcn_mfma_f32_16x16x32_bf16(a, bb, oacc[ct], 0, 0, 0);
            }
        }

        // scattered epilogue: out = x + o + bg2
        #pragma unroll
        for (int ct = 0; ct < 8; ++ct) {
            const int col = ct * 16 + lm;
            const float b2 = bg2[col];
            #pragma unroll
            for (int r = 0; r < 4; ++r) {
                const size_t o = (size_t)(row0 + q * 4 + r) * DD + col;
                out[o] = x[o] + oacc[ct][r] + b2;
            }
        }
        __syncthreads();   // protect ul reuse across grid-stride iterations
    }
}

// ===========================================================================
// PATH B (fallback): proven R5 multi-kernel pipeline
// ===========================================================================
__global__ __launch_bounds__(256) void k_zero(float4* __restrict__ p, int n4)
{
    const float4 z = {0.f, 0.f, 0.f, 0.f};
    for (int i = blockIdx.x * 256 + threadIdx.x; i < n4; i += gridDim.x * 256)
        p[i] = z;
}

__global__ __launch_bounds__(256) void k_prep(
    const float* __restrict__ x, const int* __restrict__ ei,
    const float* __restrict__ Wh1, const float* __restrict__ Wf1,
    const float* __restrict__ Wg1, const float* __restrict__ Wg2,
    unsigned short* __restrict__ xb, int* __restrict__ deg,
    unsigned short* __restrict__ pk)
{
    if (blockIdx.x < 1250) {
        const int gid = blockIdx.x * 256 + threadIdx.x;
        const int e0 = gid * 2;
        atomicAdd(&deg[ei[EE + e0]], 1);
        atomicAdd(&deg[ei[EE + e0 + 1]], 1);

        const size_t base = (size_t)gid * 16;
        ushort8 o0, o1;
        #pragma unroll
        for (int q = 0; q < 2; ++q) {
            #pragma unroll
            for (int p = 0; p < 2; ++p) {
                const float4 v = *(const float4*)(x + base + q * 8 + p * 4);
                ushort8& o = q ? o1 : o0;
                o[p * 4 + 0] = f2bf(v.x);
                o[p * 4 + 1] = f2bf(v.y);
                o[p * 4 + 2] = f2bf(v.z);
                o[p * 4 + 3] = f2bf(v.w);
            }
        }
        *(ushort8*)(xb + base)     = o0;
        *(ushort8*)(xb + base + 8) = o1;
    } else {
        const int t   = (blockIdx.x - 1250) * 256 + threadIdx.x;
        const int mat = t >> 11;
        const int rem = t & 2047;
        const int ct  = rem >> 8;
        const int kc  = (rem >> 6) & 3;
        const int l   = rem & 63;
        const float* W = (mat == 0) ? Wh1 : (mat == 1) ? (Wf1 + 3 * DD)
                       : (mat == 2) ? Wg1 : Wg2;
        const int n  = ct * 16 + (l & 15);
        const int k0 = kc * 32 + (l >> 4) * 8;
        ushort8 v;
        #pragma unroll
        for (int j = 0; j < 8; ++j) v[j] = f2bf(W[(size_t)(k0 + j) * DD + n]);
        *(ushort8*)(pk + (size_t)t * 8) = v;
    }
}

__global__ __launch_bounds__(256) void k_node_pre(
    const unsigned short* __restrict__ xb, const unsigned short* __restrict__ pk,
    const float* __restrict__ pos, const float* __restrict__ Wf1,
    const float* __restrict__ bh1, const float* __restrict__ Wh2,
    const float* __restrict__ bh2, const float* __restrict__ bf1,
    unsigned short* __restrict__ ub, float* __restrict__ delta)
{
    __shared__ float          hl[64 * 132];
    __shared__ unsigned short ul[64 * 136];
    const int t  = threadIdx.x;
    const int w  = t >> 6, l = t & 63;
    const int lm = l & 15, q = l >> 4;
    const int rowb = blockIdx.x * 64;
    const int row0 = rowb + w * 16;

    const unsigned short* pkh = pk;
    const unsigned short* pkf = pk + 16384;

    floatx4 hacc[8], facc[8];
    #pragma unroll
    for (int ct = 0; ct < 8; ++ct) { hacc[ct] = 0.f; facc[ct] = 0.f; }

    #pragma unroll
    for (int kc = 0; kc < 4; ++kc) {
        const short8 a = *(const short8*)(xb + (size_t)(row0 + lm) * DD + kc * 32 + q * 8);
        #pragma unroll
        for (int ct = 0; ct < 8; ++ct) {
            const short8 bh = *(const short8*)(pkh + (size_t)((ct * 4 + kc) * 64 + l) * 8);
            const short8 bf = *(const short8*)(pkf + (size_t)((ct * 4 + kc) * 64 + l) * 8);
            hacc[ct] = __builtin_amdgcn_mfma_f32_16x16x32_bf16(a, bh, hacc[ct], 0, 0, 0);
            facc[ct] = __builtin_amdgcn_mfma_f32_16x16x32_bf16(a, bf, facc[ct], 0, 0, 0);
        }
    }

    float px[4][3];
    #pragma unroll
    for (int r = 0; r < 4; ++r) {
        const int rr = row0 + q * 4 + r;
        px[r][0] = pos[rr * 3 + 0];
        px[r][1] = pos[rr * 3 + 1];
        px[r][2] = pos[rr * 3 + 2];
    }

    #pragma unroll
    for (int ct = 0; ct < 8; ++ct) {
        const int col = ct * 16 + lm;
        const float b1 = bh1[col];
        const float bf = bf1[col];
        const float w0 = Wf1[0 * DD + col];
        const float w1 = Wf1[1 * DD + col];
        const float w2 = Wf1[2 * DD + col];
        #pragma unroll
        for (int r = 0; r < 4; ++r) {
            const int rr = w * 16 + q * 4 + r;
            const float uv = facc[ct][r] + bf
                           + px[r][0] * w0 + px[r][1] * w1 + px[r][2] * w2;
            ul[rr * 136 + col] = f2bf(uv);
            hl[rr * 132 + col] = leaky1(hacc[ct][r] + b1);
        }
    }
    __syncthreads();

    #pragma unroll
    for (int k = 0; k < 4; ++k) {
        const int idx = t + k * 256;
        const int row = idx >> 4;
        const int c8  = (idx & 15) * 8;
        *(ushort8*)(ub + (size_t)(rowb + row) * DD + c8) =
            *(const ushort8*)(ul + row * 136 + c8);
    }

    if (t < 192) {
        const int r = t / 3, k = t - 3 * (t / 3);
        float s = bh2[k];
        for (int d = 0; d < DD; ++d) s += hl[r * 132 + d] * Wh2[d * 3 + k];
        delta[(size_t)(rowb + r) * 3 + k] = tanhf(s);
    }
}

__global__ __launch_bounds__(1024) void k_scan_up(const int* __restrict__ deg,
                                                  int* __restrict__ off,
                                                  int* __restrict__ bsum)
{
    __shared__ int wsum[16];
    const int t = threadIdx.x, b = blockIdx.x;
    const int i = b * 1024 + t;
    const int v = (i < NN) ? deg[i] : 0;
    const int lane = t & 63, w = t >> 6;

    int incl = v;
    #pragma unroll
    for (int d = 1; d < 64; d <<= 1) {
        const int o = __shfl_up(incl, d);
        if (lane >= d) incl += o;
    }
    if (lane == 63) wsum[w] = incl;
    __syncthreads();
    int wbase = 0;
    for (int k = 0; k < w; ++k) wbase += wsum[k];

    if (i < NN) off[i] = wbase + incl - v;
    if (t == 1023) bsum[b] = wbase + incl;
}

__global__ __launch_bounds__(64) void k_scan_mid(const int* __restrict__ bsum,
                                                 int* __restrict__ bbase)
{
    const int t = threadIdx.x;
    const int v = (t < 40) ? bsum[t] : 0;
    int incl = v;
    #pragma unroll
    for (int d = 1; d < 64; d <<= 1) {
        const int o = __shfl_up(incl, d);
        if (t >= d) incl += o;
    }
    if (t < 40) bbase[t] = incl - v;
}

__global__ __launch_bounds__(1024) void k_scan_add(int* __restrict__ off,
                                                   const int* __restrict__ bbase,
                                                   int* __restrict__ cur)
{
    const int t = threadIdx.x, b = blockIdx.x;
    const int i = b * 1024 + t;
    if (i < NN) {
        const int o = off[i] + bbase[b];
        off[i] = o;
        cur[i] = o;
    }
    if (i == 0) off[NN] = EE;
}

__global__ __launch_bounds__(256) void k_scatter(const int* __restrict__ ei,
                                                 int* __restrict__ cur,
                                                 int* __restrict__ esrc)
{
    const int e = blockIdx.x * 256 + threadIdx.x;
    const int src = ei[e];
    const int dst = ei[EE + e];
    const int p = atomicAdd(&cur[dst], 1);
    esrc[p] = src;
}

__global__ __launch_bounds__(256) void k_gather(
    const int* __restrict__ off, const int* __restrict__ esrc,
    const float* __restrict__ pos, const float* __restrict__ delta,
    const float* __restrict__ Wf1, const unsigned short* __restrict__ ub,
    unsigned short* __restrict__ aggrb)
{
    const int t    = threadIdx.x;
    const int lane = t & 63;
    const int n    = blockIdx.x * 4 + (t >> 6);
    const int c2   = lane * 2;

    const float2 w0 = *(const float2*)(Wf1 + 0 * DD + c2);
    const float2 w1 = *(const float2*)(Wf1 + 1 * DD + c2);
    const float2 w2 = *(const float2*)(Wf1 + 2 * DD + c2);

    const float q0 = delta[n * 3 + 0] - pos[n * 3 + 0];
    const float q1 = delta[n * 3 + 1] - pos[n * 3 + 1];
    const float q2 = delta[n * 3 + 2] - pos[n * 3 + 2];

    const float v0 = q0 * w0.x + q1 * w1.x + q2 * w2.x;
    const float v1 = q0 * w0.y + q1 * w1.y + q2 * w2.y;

    float a0 = 0.f, a1 = 0.f, b0 = 0.f, b1 = 0.f;
    const int beg = off[n], end = off[n + 1];

#define EDGE_ACC(U, A0, A1)                                            \
    {                                                                  \
        const float e0 = __uint_as_float((U) << 16) + v0;              \
        const float e1 = __uint_as_float((U) & 0xffff0000u) + v1;      \
        A0 += leaky1(e0);                                              \
        A1 += leaky1(e1);                                              \
    }

    int j = beg;
    for (; j + 3 < end; j += 4) {
        const int s0 = esrc[j];
        const int s1 = esrc[j + 1];
        const int s2 = esrc[j + 2];
        const int s3 = esrc[j + 3];
        const unsigned int u0 = *(const unsigned int*)(ub + (size_t)s0 * DD + c2);
        const unsigned int u1 = *(const unsigned int*)(ub + (size_t)s1 * DD + c2);
        const unsigned int u2 = *(const unsigned int*)(ub + (size_t)s2 * DD + c2);
        const unsigned int u3 = *(const unsigned int*)(ub + (size_t)s3 * DD + c2);
        EDGE_ACC(u0, a0, a1)
        EDGE_ACC(u1, b0, b1)
        EDGE_ACC(u2, a0, a1)
        EDGE_ACC(u3, b0, b1)
    }
    for (; j < end; ++j) {
        const int s0 = esrc[j];
        const unsigned int u0 = *(const unsigned int*)(ub + (size_t)s0 * DD + c2);
        EDGE_ACC(u0, a0, a1)
    }
#undef EDGE_ACC

    a0 += b0; a1 += b1;
    const unsigned int st = ((unsigned int)f2bf(a1) << 16) | (unsigned int)f2bf(a0);
    *(unsigned int*)(aggrb + (size_t)n * DD + c2) = st;
}

__global__ __launch_bounds__(256) void k_node_out(
    const unsigned short* __restrict__ aggrb, const unsigned short* __restrict__ pk,
    const float* __restrict__ x,
    const float* __restrict__ bg1, const float* __restrict__ bg2,
    float* __restrict__ out)
{
    __shared__ unsigned short gl[64 * 136];
    __shared__ float          ol[64 * 132];
    const int t  = threadIdx.x;
    const int w  = t >> 6, l = t & 63;
    const int lm = l & 15, q = l >> 4;
    const int rowb = blockIdx.x * 64;
    const int row0 = rowb + w * 16;

    const unsigned short* pkg1 = pk + 32768;
    const unsigned short* pkg2 = pk + 49152;

    floatx4 gacc[8];
    #pragma unroll
    for (int ct = 0; ct < 8; ++ct) gacc[ct] = 0.f;

    #pragma unroll
    for (int kc = 0; kc < 4; ++kc) {
        const short8 a = *(const short8*)(aggrb + (size_t)(row0 + lm) * DD + kc * 32 + q * 8);
        #pragma unroll
        for (int ct = 0; ct < 8; ++ct) {
            const short8 b = *(const short8*)(pkg1 + (size_t)((ct * 4 + kc) * 64 + l) * 8);
            gacc[ct] = __builtin_amdgcn_mfma_f32_16x16x32_bf16(a, b, gacc[ct], 0, 0, 0);
        }
    }

    #pragma unroll
    for (int ct = 0; ct < 8; ++ct) {
        const int col = ct * 16 + lm;
        const float b1 = bg1[col];
        #pragma unroll
        for (int r = 0; r < 4; ++r)
            gl[(w * 16 + q * 4 + r) * 136 + col] = f2bf(leaky1(gacc[ct][r] + b1));
    }
    __syncthreads();

    floatx4 oacc[8];
    #pragma unroll
    for (int ct = 0; ct < 8; ++ct) oacc[ct] = 0.f;

    #pragma unroll
    for (int kc = 0; kc < 4; ++kc) {
        const short8 a = *(const short8*)(gl + (size_t)(w * 16 + lm) * 136 + kc * 32 + q * 8);
        #pragma unroll
        for (int ct = 0; ct < 8; ++ct) {
            const short8 b = *(const short8*)(pkg2 + (size_t)((ct * 4 + kc) * 64 + l) * 8);
            oacc[ct] = __builtin_amdgcn_mfma_f32_16x16x32_bf16(a, b, oacc[ct], 0, 0, 0);
        }
    }

    __syncthreads();
    #pragma unroll
    for (int ct = 0; ct < 8; ++ct) {
        const int col = ct * 16 + lm;
        #pragma unroll
        for (int r = 0; r < 4; ++r)
            ol[(w * 16 + q * 4 + r) * 132 + col] = oacc[ct][r];
    }
    __syncthreads();

    #pragma unroll
    for (int k = 0; k < 8; ++k) {
        const int idx = t + k * 256;
        const int row = idx >> 5;
        const int c4  = (idx & 31) * 4;
        const float4 ov = *(const float4*)(ol + row * 132 + c4);
        const float4 bv = *(const float4*)(bg2 + c4);
        const size_t o  = (size_t)(rowb + row) * DD + c4;
        const float4 xv = *(const float4*)(x + o);
        float4 rv;
        rv.x = xv.x + ov.x + bv.x;
        rv.y = xv.y + ov.y + bv.y;
        rv.z = xv.z + ov.z + bv.z;
        rv.w = xv.w + ov.w + bv.w;
        *(float4*)(out + o) = rv;
    }
}

// ---------------------------------------------------------------------------
extern "C" void kernel_launch(void* const* d_in, const int* in_sizes, int n_in,
                              void* d_out, int out_size, void* d_ws, size_t ws_size,
                              hipStream_t stream)
{
    const float* x   = (const float*)d_in[0];
    const float* pos = (const float*)d_in[1];
    const int*   ei  = (const int*)d_in[2];
    const float* Wh1 = (const float*)d_in[3];
    const float* bh1 = (const float*)d_in[4];
    const float* Wh2 = (const float*)d_in[5];
    const float* bh2 = (const float*)d_in[6];
    const float* Wf1 = (const float*)d_in[7];
    const float* bf1 = (const float*)d_in[8];
    const float* Wg1 = (const float*)d_in[9];
    const float* bg1 = (const float*)d_in[10];
    const float* Wg2 = (const float*)d_in[11];
    const float* bg2 = (const float*)d_in[12];
    float* out = (float*)d_out;

    unsigned short* xb    = (unsigned short*)d_ws;          // NN*DD bf16
    unsigned short* ub    = xb + (size_t)NN * DD;           // NN*DD bf16
    unsigned short* aggrb = ub + (size_t)NN * DD;           // NN*DD bf16
    unsigned short* pk    = aggrb + (size_t)NN * DD;        // 4*16384 bf16
    float* delta = (float*)(pk + 65536);                    // NN*3
    int*   deg   = (int*)(delta + (size_t)NN * 3);          // NN
    int*   off   = deg + NN;                                // NN+4
    int*   cur   = off + NN + 4;                            // NN
    int*   esrc  = cur + NN;                                // EE
    int*   bsum  = esrc + EE;                               // 40
    int*   bbase = bsum + 40;                               // 40

    void* args[] = {
        (void*)&x, (void*)&pos, (void*)&ei,
        (void*)&Wh1, (void*)&bh1, (void*)&Wh2, (void*)&bh2,
        (void*)&Wf1, (void*)&bf1, (void*)&Wg1, (void*)&bg1,
        (void*)&Wg2, (void*)&bg2, (void*)&out,
        (void*)&xb, (void*)&ub, (void*)&aggrb, (void*)&pk,
        (void*)&delta, (void*)&deg, (void*)&off, (void*)&cur,
        (void*)&esrc, (void*)&bsum
    };
    hipError_t err = hipLaunchCooperativeKernel((const void*)k_mega, dim3(GRID),
                                                dim3(TPB), args, 0, stream);
    if (err != hipSuccess) {
        (void)hipGetLastError();   // clear sticky error, run fallback path
        k_zero<<<40, 256, 0, stream>>>((float4*)deg, NN / 4);
        k_prep<<<1282, 256, 0, stream>>>(x, ei, Wh1, Wf1, Wg1, Wg2, xb, deg, pk);
        k_node_pre<<<NN / 64, 256, 0, stream>>>(xb, pk, pos, Wf1, bh1, Wh2, bh2,
                                                bf1, ub, delta);
        k_scan_up<<<40, 1024, 0, stream>>>(deg, off, bsum);
        k_scan_mid<<<1, 64, 0, stream>>>(bsum, bbase);
        k_scan_add<<<40, 1024, 0, stream>>>(off, bbase, cur);
        k_scatter<<<EE / 256, 256, 0, stream>>>(ei, cur, esrc);
        k_gather<<<NN / 4, 256, 0, stream>>>(off, esrc, pos, delta, Wf1, ub, aggrb);
        k_node_out<<<NN / 64, 256, 0, stream>>>(aggrb, pk, x, bg1, bg2, out);
    }
}

// Round 8
// 233.410 us; speedup vs baseline: 3.8902x; 3.8902x over previous
//
#include <hip/hip_runtime.h>

#define NN 40000
#define DD 128
#define EE 640000
#define SLOPE 0.01f

typedef __attribute__((ext_vector_type(8))) short  short8;   // 8 x bf16
typedef __attribute__((ext_vector_type(8))) unsigned short ushort8;
typedef __attribute__((ext_vector_type(4))) float  floatx4;  // MFMA acc

__device__ __forceinline__ float leaky1(float v) { return v >= 0.f ? v : v * SLOPE; }

__device__ __forceinline__ unsigned short f2bf(float f) {
    unsigned int u = __float_as_uint(f);
    u += 0x7fffu + ((u >> 16) & 1u);       // RNE
    return (unsigned short)(u >> 16);
}

// ---------------------------------------------------------------------------
// K0 k_init: deg=0, donecnt=0, pack 4 weight mats into bf16 MFMA B-frag order
//   pk[mat][(ct*4+kc)*64 + lane] : 8 elems = W[kc*32+(lane>>4)*8+j][ct*16+(lane&15)]
// 160 blocks x 256 = 40960 threads.
// ---------------------------------------------------------------------------
__global__ __launch_bounds__(256) void k_init(
    const float* __restrict__ Wh1, const float* __restrict__ Wf1,
    const float* __restrict__ Wg1, const float* __restrict__ Wg2,
    int* __restrict__ deg, int* __restrict__ donecnt,
    unsigned short* __restrict__ pk)
{
    const int gid = blockIdx.x * 256 + threadIdx.x;
    if (gid < NN) deg[gid] = 0;
    if (gid == 0) *donecnt = 0;

    if (gid < 8192) {
        const int mat = gid >> 11;
        const int rem = gid & 2047;
        const int ct  = rem >> 8;
        const int kc  = (rem >> 6) & 3;
        const int l   = rem & 63;
        const float* W = (mat == 0) ? Wh1 : (mat == 1) ? (Wf1 + 3 * DD)
                       : (mat == 2) ? Wg1 : Wg2;
        const int n  = ct * 16 + (l & 15);
        const int k0 = kc * 32 + (l >> 4) * 8;
        ushort8 v;
        #pragma unroll
        for (int j = 0; j < 8; ++j) v[j] = f2bf(W[(size_t)(k0 + j) * DD + n]);
        *(ushort8*)(pk + (size_t)gid * 8) = v;
    }
}

// ---------------------------------------------------------------------------
// K1 k_node_pre: fused histogram + MFMA node precompute (inline x->bf16).
//   deg[dst]++ (4 edges/thread, fire-and-forget)
//   h     = leaky(x@Wh1 + bh1)     (registers only)
//   delta = tanh(h@Wh2 + bh2)      -> global (via quad shfl reduction)
//   u     = bf16(x@Wf1[3:] + bf1 + pos@Wf1[0:3]) -> global (LDS-coalesced)
// 625 blocks x 256, 64 rows/block.
// ---------------------------------------------------------------------------
__global__ __launch_bounds__(256) void k_node_pre(
    const float* __restrict__ x, const int* __restrict__ ei,
    const unsigned short* __restrict__ pk,
    const float* __restrict__ pos, const float* __restrict__ Wf1,
    const float* __restrict__ bh1, const float* __restrict__ Wh2,
    const float* __restrict__ bh2, const float* __restrict__ bf1,
    int* __restrict__ deg, unsigned short* __restrict__ ub,
    float* __restrict__ delta)
{
    __shared__ unsigned short ul[64 * 136];   // bf16 u tile
    const int t  = threadIdx.x;
    const int w  = t >> 6, l = t & 63;
    const int lm = l & 15, q = l >> 4;
    const int rowb = blockIdx.x * 64;
    const int row0 = rowb + w * 16;

    // fused histogram: 4 edges/thread
    {
        const int e0 = (blockIdx.x * 256 + t) * 4;
        atomicAdd(&deg[ei[EE + e0 + 0]], 1);
        atomicAdd(&deg[ei[EE + e0 + 1]], 1);
        atomicAdd(&deg[ei[EE + e0 + 2]], 1);
        atomicAdd(&deg[ei[EE + e0 + 3]], 1);
    }

    const unsigned short* pkh = pk;            // Wh1
    const unsigned short* pkf = pk + 16384;    // Wf1[3:]

    floatx4 hacc[8], facc[8];
    #pragma unroll
    for (int ct = 0; ct < 8; ++ct) { hacc[ct] = 0.f; facc[ct] = 0.f; }

    #pragma unroll
    for (int kc = 0; kc < 4; ++kc) {
        // inline fp32->bf16 A-frag: x[row0+lm][kc*32+q*8 .. +8]
        const float* xp = x + (size_t)(row0 + lm) * DD + kc * 32 + q * 8;
        const float4 v0 = *(const float4*)(xp);
        const float4 v1 = *(const float4*)(xp + 4);
        ushort8 au;
        au[0] = f2bf(v0.x); au[1] = f2bf(v0.y); au[2] = f2bf(v0.z); au[3] = f2bf(v0.w);
        au[4] = f2bf(v1.x); au[5] = f2bf(v1.y); au[6] = f2bf(v1.z); au[7] = f2bf(v1.w);
        const short8 a = *(short8*)&au;
        #pragma unroll
        for (int ct = 0; ct < 8; ++ct) {
            const short8 bh = *(const short8*)(pkh + (size_t)((ct * 4 + kc) * 64 + l) * 8);
            const short8 bf = *(const short8*)(pkf + (size_t)((ct * 4 + kc) * 64 + l) * 8);
            hacc[ct] = __builtin_amdgcn_mfma_f32_16x16x32_bf16(a, bh, hacc[ct], 0, 0, 0);
            facc[ct] = __builtin_amdgcn_mfma_f32_16x16x32_bf16(a, bf, facc[ct], 0, 0, 0);
        }
    }

    float px[4][3];
    #pragma unroll
    for (int r = 0; r < 4; ++r) {
        const int rr = row0 + q * 4 + r;
        px[r][0] = pos[rr * 3 + 0];
        px[r][1] = pos[rr * 3 + 1];
        px[r][2] = pos[rr * 3 + 2];
    }

    // D layout: row=q*4+r, col=ct*16+lm (m89/m91-verified).
    // u -> LDS; delta partials in registers.
    float p[4][3] = {};
    #pragma unroll
    for (int ct = 0; ct < 8; ++ct) {
        const int col = ct * 16 + lm;
        const float b1  = bh1[col];
        const float bfv = bf1[col];
        const float w0 = Wf1[0 * DD + col];
        const float w1 = Wf1[1 * DD + col];
        const float w2 = Wf1[2 * DD + col];
        const float wh20 = Wh2[col * 3 + 0];
        const float wh21 = Wh2[col * 3 + 1];
        const float wh22 = Wh2[col * 3 + 2];
        #pragma unroll
        for (int r = 0; r < 4; ++r) {
            const float uv = facc[ct][r] + bfv
                           + px[r][0] * w0 + px[r][1] * w1 + px[r][2] * w2;
            ul[(w * 16 + q * 4 + r) * 136 + col] = f2bf(uv);
            const float hv = leaky1(hacc[ct][r] + b1);
            p[r][0] += hv * wh20;
            p[r][1] += hv * wh21;
            p[r][2] += hv * wh22;
        }
    }
    // reduce delta partials over the 16 lanes of this quad (lane bits 0..3)
    #pragma unroll
    for (int m = 1; m < 16; m <<= 1) {
        #pragma unroll
        for (int r = 0; r < 4; ++r) {
            #pragma unroll
            for (int k = 0; k < 3; ++k)
                p[r][k] += __shfl_xor(p[r][k], m);
        }
    }
    if (lm < 12) {
        const int r = lm / 3, k = lm - 3 * (lm / 3);
        delta[(size_t)(row0 + q * 4 + r) * 3 + k] = tanhf(p[r][k] + bh2[k]);
    }

    __syncthreads();
    // coalesced u store: 1024 x 16B chunks
    #pragma unroll
    for (int k = 0; k < 4; ++k) {
        const int idx = t + k * 256;
        const int row = idx >> 4;
        const int c8  = (idx & 15) * 8;
        *(ushort8*)(ub + (size_t)(rowb + row) * DD + c8) =
            *(const ushort8*)(ul + row * 136 + c8);
    }
}

// ---------------------------------------------------------------------------
// K2 k_scan: single-dispatch exclusive scan of deg[NN] -> off/cur.
// 40 blocks x 1024, 1000 elems/block (coalesced 1/thread).
// Cross-block: publish bsum (release, agent scope), spin on donecnt
// (all 40 blocks co-resident -> safe), then each block adds its prefix.
// ---------------------------------------------------------------------------
__global__ __launch_bounds__(1024) void k_scan(
    const int* __restrict__ deg, int* __restrict__ off, int* __restrict__ cur,
    int* __restrict__ bsum, int* __restrict__ donecnt)
{
    __shared__ int wsum[16];
    __shared__ int sbb;
    const int t = threadIdx.x, b = blockIdx.x;
    const int lane = t & 63, w = t >> 6;
    const int i = b * 1000 + t;

    const int v = (t < 1000) ? deg[i] : 0;
    int incl = v;
    #pragma unroll
    for (int d = 1; d < 64; d <<= 1) {
        const int o = __shfl_up(incl, d);
        if (lane >= d) incl += o;
    }
    if (lane == 63) wsum[w] = incl;
    __syncthreads();
    int wbase = 0;
    for (int k = 0; k < w; ++k) wbase += wsum[k];
    const int excl = wbase + incl - v;

    if (t == 0) {
        int tot = 0;
        #pragma unroll
        for (int k = 0; k < 16; ++k) tot += wsum[k];
        __hip_atomic_store(&bsum[b], tot, __ATOMIC_RELEASE, __HIP_MEMORY_SCOPE_AGENT);
        __hip_atomic_fetch_add(donecnt, 1, __ATOMIC_RELEASE, __HIP_MEMORY_SCOPE_AGENT);
        // spin until all 40 blocks have published (all co-resident)
        while (__hip_atomic_load(donecnt, __ATOMIC_ACQUIRE, __HIP_MEMORY_SCOPE_AGENT) < 40)
            __builtin_amdgcn_s_sleep(8);
        int bb = 0;
        for (int k = 0; k < b; ++k)
            bb += __hip_atomic_load(&bsum[k], __ATOMIC_RELAXED, __HIP_MEMORY_SCOPE_AGENT);
        sbb = bb;
    }
    __syncthreads();
    const int bb = sbb;

    if (t < 1000) {
        const int o = excl + bb;
        off[i] = o;
        cur[i] = o;
    }
    if (b == 0 && t == 0) off[NN] = EE;
}

// ---------------------------------------------------------------------------
// K3 k_scatter: bucket src indices by dst (CSR fill)
// ---------------------------------------------------------------------------
__global__ __launch_bounds__(256) void k_scatter(const int* __restrict__ ei,
                                                 int* __restrict__ cur,
                                                 int* __restrict__ esrc)
{
    const int e = blockIdx.x * 256 + threadIdx.x;
    const int src = ei[e];
    const int dst = ei[EE + e];
    const int p = atomicAdd(&cur[dst], 1);
    esrc[p] = src;
}

// ---------------------------------------------------------------------------
// K4 k_gather: pull-mode aggregation. One wave per dst node, 2 cols/lane.
//   v        = (delta[n]-pos[n]) @ Wf1[0:3,:]   (once per node)
//   aggrb[n] = bf16( sum_e leaky(ub[src_e] + v) )
// ---------------------------------------------------------------------------
__global__ __launch_bounds__(256) void k_gather(
    const int* __restrict__ off, const int* __restrict__ esrc,
    const float* __restrict__ pos, const float* __restrict__ delta,
    const float* __restrict__ Wf1, const unsigned short* __restrict__ ub,
    unsigned short* __restrict__ aggrb)
{
    const int t    = threadIdx.x;
    const int lane = t & 63;
    const int n    = blockIdx.x * 4 + (t >> 6);
    const int c2   = lane * 2;

    const float2 w0 = *(const float2*)(Wf1 + 0 * DD + c2);
    const float2 w1 = *(const float2*)(Wf1 + 1 * DD + c2);
    const float2 w2 = *(const float2*)(Wf1 + 2 * DD + c2);

    const float q0 = delta[n * 3 + 0] - pos[n * 3 + 0];
    const float q1 = delta[n * 3 + 1] - pos[n * 3 + 1];
    const float q2 = delta[n * 3 + 2] - pos[n * 3 + 2];

    const float v0 = q0 * w0.x + q1 * w1.x + q2 * w2.x;
    const float v1 = q0 * w0.y + q1 * w1.y + q2 * w2.y;

    float a0 = 0.f, a1 = 0.f, b0 = 0.f, b1 = 0.f;
    const int beg = off[n], end = off[n + 1];

#define EDGE_ACC(U, A0, A1)                                            \
    {                                                                  \
        const float e0 = __uint_as_float((U) << 16) + v0;              \
        const float e1 = __uint_as_float((U) & 0xffff0000u) + v1;      \
        A0 += leaky1(e0);                                              \
        A1 += leaky1(e1);                                              \
    }

    int j = beg;
    for (; j + 3 < end; j += 4) {
        const int s0 = esrc[j];
        const int s1 = esrc[j + 1];
        const int s2 = esrc[j + 2];
        const int s3 = esrc[j + 3];
        const unsigned int u0 = *(const unsigned int*)(ub + (size_t)s0 * DD + c2);
        const unsigned int u1 = *(const unsigned int*)(ub + (size_t)s1 * DD + c2);
        const unsigned int u2 = *(const unsigned int*)(ub + (size_t)s2 * DD + c2);
        const unsigned int u3 = *(const unsigned int*)(ub + (size_t)s3 * DD + c2);
        EDGE_ACC(u0, a0, a1)
        EDGE_ACC(u1, b0, b1)
        EDGE_ACC(u2, a0, a1)
        EDGE_ACC(u3, b0, b1)
    }
    for (; j < end; ++j) {
        const int s0 = esrc[j];
        const unsigned int u0 = *(const unsigned int*)(ub + (size_t)s0 * DD + c2);
        EDGE_ACC(u0, a0, a1)
    }
#undef EDGE_ACC

    a0 += b0; a1 += b1;
    const unsigned int st = ((unsigned int)f2bf(a1) << 16) | (unsigned int)f2bf(a0);
    *(unsigned int*)(aggrb + (size_t)n * DD + c2) = st;
}

// ---------------------------------------------------------------------------
// K5 k_node_out: MFMA node update, LDS-coalesced epilogue.
//   g   = leaky(aggr@Wg1 + bg1);  out = x + g@Wg2 + bg2
// ---------------------------------------------------------------------------
__global__ __launch_bounds__(256) void k_node_out(
    const unsigned short* __restrict__ aggrb, const unsigned short* __restrict__ pk,
    const float* __restrict__ x,
    const float* __restrict__ bg1, const float* __restrict__ bg2,
    float* __restrict__ out)
{
    __shared__ unsigned short gl[64 * 136];
    __shared__ float          ol[64 * 132];
    const int t  = threadIdx.x;
    const int w  = t >> 6, l = t & 63;
    const int lm = l & 15, q = l >> 4;
    const int rowb = blockIdx.x * 64;
    const int row0 = rowb + w * 16;

    const unsigned short* pkg1 = pk + 32768;
    const unsigned short* pkg2 = pk + 49152;

    floatx4 gacc[8];
    #pragma unroll
    for (int ct = 0; ct < 8; ++ct) gacc[ct] = 0.f;

    #pragma unroll
    for (int kc = 0; kc < 4; ++kc) {
        const short8 a = *(const short8*)(aggrb + (size_t)(row0 + lm) * DD + kc * 32 + q * 8);
        #pragma unroll
        for (int ct = 0; ct < 8; ++ct) {
            const short8 b = *(const short8*)(pkg1 + (size_t)((ct * 4 + kc) * 64 + l) * 8);
            gacc[ct] = __builtin_amdgcn_mfma_f32_16x16x32_bf16(a, b, gacc[ct], 0, 0, 0);
        }
    }

    #pragma unroll
    for (int ct = 0; ct < 8; ++ct) {
        const int col = ct * 16 + lm;
        const float b1 = bg1[col];
        #pragma unroll
        for (int r = 0; r < 4; ++r)
            gl[(w * 16 + q * 4 + r) * 136 + col] = f2bf(leaky1(gacc[ct][r] + b1));
    }
    __syncthreads();

    floatx4 oacc[8];
    #pragma unroll
    for (int ct = 0; ct < 8; ++ct) oacc[ct] = 0.f;

    #pragma unroll
    for (int kc = 0; kc < 4; ++kc) {
        const short8 a = *(const short8*)(gl + (size_t)(w * 16 + lm) * 136 + kc * 32 + q * 8);
        #pragma unroll
        for (int ct = 0; ct < 8; ++ct) {
            const short8 b = *(const short8*)(pkg2 + (size_t)((ct * 4 + kc) * 64 + l) * 8);
            oacc[ct] = __builtin_amdgcn_mfma_f32_16x16x32_bf16(a, b, oacc[ct], 0, 0, 0);
        }
    }

    __syncthreads();
    #pragma unroll
    for (int ct = 0; ct < 8; ++ct) {
        const int col = ct * 16 + lm;
        #pragma unroll
        for (int r = 0; r < 4; ++r)
            ol[(w * 16 + q * 4 + r) * 132 + col] = oacc[ct][r];
    }
    __syncthreads();

    #pragma unroll
    for (int k = 0; k < 8; ++k) {
        const int idx = t + k * 256;
        const int row = idx >> 5;
        const int c4  = (idx & 31) * 4;
        const float4 ov = *(const float4*)(ol + row * 132 + c4);
        const float4 bv = *(const float4*)(bg2 + c4);
        const size_t o  = (size_t)(rowb + row) * DD + c4;
        const float4 xv = *(const float4*)(x + o);
        float4 rv;
        rv.x = xv.x + ov.x + bv.x;
        rv.y = xv.y + ov.y + bv.y;
        rv.z = xv.z + ov.z + bv.z;
        rv.w = xv.w + ov.w + bv.w;
        *(float4*)(out + o) = rv;
    }
}

// ---------------------------------------------------------------------------
extern "C" void kernel_launch(void* const* d_in, const int* in_sizes, int n_in,
                              void* d_out, int out_size, void* d_ws, size_t ws_size,
                              hipStream_t stream)
{
    const float* x   = (const float*)d_in[0];
    const float* pos = (const float*)d_in[1];
    const int*   ei  = (const int*)d_in[2];
    const float* Wh1 = (const float*)d_in[3];
    const float* bh1 = (const float*)d_in[4];
    const float* Wh2 = (const float*)d_in[5];
    const float* bh2 = (const float*)d_in[6];
    const float* Wf1 = (const float*)d_in[7];
    const float* bf1 = (const float*)d_in[8];
    const float* Wg1 = (const float*)d_in[9];
    const float* bg1 = (const float*)d_in[10];
    const float* Wg2 = (const float*)d_in[11];
    const float* bg2 = (const float*)d_in[12];
    float* out = (float*)d_out;

    unsigned short* ub    = (unsigned short*)d_ws;          // NN*DD bf16
    unsigned short* aggrb = ub + (size_t)NN * DD;           // NN*DD bf16
    unsigned short* pk    = aggrb + (size_t)NN * DD;        // 4*16384 bf16
    float* delta   = (float*)(pk + 65536);                  // NN*3
    int*   deg     = (int*)(delta + (size_t)NN * 3);        // NN
    int*   off     = deg + NN;                              // NN+4
    int*   cur     = off + NN + 4;                          // NN
    int*   esrc    = cur + NN;                              // EE
    int*   bsum    = esrc + EE;                             // 40
    int*   donecnt = bsum + 40;                             // 1

    k_init<<<160, 256, 0, stream>>>(Wh1, Wf1, Wg1, Wg2, deg, donecnt, pk);
    k_node_pre<<<NN / 64, 256, 0, stream>>>(x, ei, pk, pos, Wf1, bh1, Wh2, bh2,
                                            bf1, deg, ub, delta);
    k_scan<<<40, 1024, 0, stream>>>(deg, off, cur, bsum, donecnt);
    k_scatter<<<EE / 256, 256, 0, stream>>>(ei, cur, esrc);
    k_gather<<<NN / 4, 256, 0, stream>>>(off, esrc, pos, delta, Wf1, ub, aggrb);
    k_node_out<<<NN / 64, 256, 0, stream>>>(aggrb, pk, x, bg1, bg2, out);
}

// Round 9
// 214.844 us; speedup vs baseline: 4.2264x; 1.0864x over previous
//
#include <hip/hip_runtime.h>

#define NN 40000
#define DD 128
#define EE 640000
#define SLOPE 0.01f

typedef __attribute__((ext_vector_type(8))) short  short8;   // 8 x bf16
typedef __attribute__((ext_vector_type(8))) unsigned short ushort8;
typedef __attribute__((ext_vector_type(4))) float  floatx4;  // MFMA acc

__device__ __forceinline__ float leaky1(float v) { return v >= 0.f ? v : v * SLOPE; }

__device__ __forceinline__ unsigned short f2bf(float f) {
    unsigned int u = __float_as_uint(f);
    u += 0x7fffu + ((u >> 16) & 1u);       // RNE
    return (unsigned short)(u >> 16);
}

// ---------------------------------------------------------------------------
// K0 k_init: deg=0, donecnt=0, pack 4 weight mats into bf16 MFMA B-frag order
// ---------------------------------------------------------------------------
__global__ __launch_bounds__(256) void k_init(
    const float* __restrict__ Wh1, const float* __restrict__ Wf1,
    const float* __restrict__ Wg1, const float* __restrict__ Wg2,
    int* __restrict__ deg, int* __restrict__ donecnt,
    unsigned short* __restrict__ pk)
{
    const int gid = blockIdx.x * 256 + threadIdx.x;
    if (gid < NN) deg[gid] = 0;
    if (gid == 0) *donecnt = 0;

    if (gid < 8192) {
        const int mat = gid >> 11;
        const int rem = gid & 2047;
        const int ct  = rem >> 8;
        const int kc  = (rem >> 6) & 3;
        const int l   = rem & 63;
        const float* W = (mat == 0) ? Wh1 : (mat == 1) ? (Wf1 + 3 * DD)
                       : (mat == 2) ? Wg1 : Wg2;
        const int n  = ct * 16 + (l & 15);
        const int k0 = kc * 32 + (l >> 4) * 8;
        ushort8 v;
        #pragma unroll
        for (int j = 0; j < 8; ++j) v[j] = f2bf(W[(size_t)(k0 + j) * DD + n]);
        *(ushort8*)(pk + (size_t)gid * 8) = v;
    }
}

// ---------------------------------------------------------------------------
// K1 k_node_pre: function-split for occupancy (1250 blocks, 5000 waves).
//   all blocks: deg[dst]++ for 2 edges/thread
//   blocks   0..624: u = bf16(x@Wf1[3:] + bf1 + pos@Wf1[0:3]) -> LDS-coalesced
//   blocks 625..1249: h = leaky(x@Wh1+bh1); delta = tanh(h@Wh2+bh2) via shfl
// Each block: 64 rows, one 8-tile MFMA acc set (half of R8's chain).
// ---------------------------------------------------------------------------
__global__ __launch_bounds__(256) void k_node_pre(
    const float* __restrict__ x, const int* __restrict__ ei,
    const unsigned short* __restrict__ pk,
    const float* __restrict__ pos, const float* __restrict__ Wf1,
    const float* __restrict__ bh1, const float* __restrict__ Wh2,
    const float* __restrict__ bh2, const float* __restrict__ bf1,
    int* __restrict__ deg, unsigned short* __restrict__ ub,
    float* __restrict__ delta)
{
    __shared__ unsigned short ul[64 * 136];   // used by u-path only
    const int t  = threadIdx.x;
    const int w  = t >> 6, l = t & 63;
    const int lm = l & 15, q = l >> 4;
    const bool upath = blockIdx.x < 625;
    const int tile = upath ? blockIdx.x : blockIdx.x - 625;
    const int rowb = tile * 64;
    const int row0 = rowb + w * 16;

    // fused histogram: 2 edges/thread across 1250 blocks
    {
        const int e0 = (blockIdx.x * 256 + t) * 2;
        atomicAdd(&deg[ei[EE + e0 + 0]], 1);
        atomicAdd(&deg[ei[EE + e0 + 1]], 1);
    }

    const unsigned short* pkm = upath ? (pk + 16384) : pk;   // Wf1[3:] / Wh1

    floatx4 acc[8];
    #pragma unroll
    for (int ct = 0; ct < 8; ++ct) acc[ct] = 0.f;

    #pragma unroll
    for (int kc = 0; kc < 4; ++kc) {
        // inline fp32->bf16 A-frag: x[row0+lm][kc*32+q*8 .. +8]
        const float* xp = x + (size_t)(row0 + lm) * DD + kc * 32 + q * 8;
        const float4 v0 = *(const float4*)(xp);
        const float4 v1 = *(const float4*)(xp + 4);
        ushort8 au;
        au[0] = f2bf(v0.x); au[1] = f2bf(v0.y); au[2] = f2bf(v0.z); au[3] = f2bf(v0.w);
        au[4] = f2bf(v1.x); au[5] = f2bf(v1.y); au[6] = f2bf(v1.z); au[7] = f2bf(v1.w);
        const short8 a = *(short8*)&au;
        #pragma unroll
        for (int ct = 0; ct < 8; ++ct) {
            const short8 b = *(const short8*)(pkm + (size_t)((ct * 4 + kc) * 64 + l) * 8);
            acc[ct] = __builtin_amdgcn_mfma_f32_16x16x32_bf16(a, b, acc[ct], 0, 0, 0);
        }
    }

    // D layout: row=q*4+r, col=ct*16+lm (m89/m91-verified)
    if (upath) {
        float px[4][3];
        #pragma unroll
        for (int r = 0; r < 4; ++r) {
            const int rr = row0 + q * 4 + r;
            px[r][0] = pos[rr * 3 + 0];
            px[r][1] = pos[rr * 3 + 1];
            px[r][2] = pos[rr * 3 + 2];
        }
        #pragma unroll
        for (int ct = 0; ct < 8; ++ct) {
            const int col = ct * 16 + lm;
            const float bfv = bf1[col];
            const float w0 = Wf1[0 * DD + col];
            const float w1 = Wf1[1 * DD + col];
            const float w2 = Wf1[2 * DD + col];
            #pragma unroll
            for (int r = 0; r < 4; ++r) {
                const float uv = acc[ct][r] + bfv
                               + px[r][0] * w0 + px[r][1] * w1 + px[r][2] * w2;
                ul[(w * 16 + q * 4 + r) * 136 + col] = f2bf(uv);
            }
        }
        __syncthreads();
        // coalesced u store: 1024 x 16B chunks
        #pragma unroll
        for (int k = 0; k < 4; ++k) {
            const int idx = t + k * 256;
            const int row = idx >> 4;
            const int c8  = (idx & 15) * 8;
            *(ushort8*)(ub + (size_t)(rowb + row) * DD + c8) =
                *(const ushort8*)(ul + row * 136 + c8);
        }
    } else {
        float p[4][3] = {};
        #pragma unroll
        for (int ct = 0; ct < 8; ++ct) {
            const int col = ct * 16 + lm;
            const float b1 = bh1[col];
            const float wh20 = Wh2[col * 3 + 0];
            const float wh21 = Wh2[col * 3 + 1];
            const float wh22 = Wh2[col * 3 + 2];
            #pragma unroll
            for (int r = 0; r < 4; ++r) {
                const float hv = leaky1(acc[ct][r] + b1);
                p[r][0] += hv * wh20;
                p[r][1] += hv * wh21;
                p[r][2] += hv * wh22;
            }
        }
        // reduce over the 16 lanes of this quad (lane bits 0..3)
        #pragma unroll
        for (int m = 1; m < 16; m <<= 1) {
            #pragma unroll
            for (int r = 0; r < 4; ++r) {
                #pragma unroll
                for (int k = 0; k < 3; ++k)
                    p[r][k] += __shfl_xor(p[r][k], m);
            }
        }
        if (lm < 12) {
            const int r = lm / 3, k = lm - 3 * (lm / 3);
            delta[(size_t)(row0 + q * 4 + r) * 3 + k] = tanhf(p[r][k] + bh2[k]);
        }
    }
}

// ---------------------------------------------------------------------------
// K2 k_scan: single-dispatch exclusive scan of deg[NN] -> off/cur.
// 40 blocks x 1024; cross-block via release/acquire spin (all co-resident).
// ---------------------------------------------------------------------------
__global__ __launch_bounds__(1024) void k_scan(
    const int* __restrict__ deg, int* __restrict__ off, int* __restrict__ cur,
    int* __restrict__ bsum, int* __restrict__ donecnt)
{
    __shared__ int wsum[16];
    __shared__ int sbb;
    const int t = threadIdx.x, b = blockIdx.x;
    const int lane = t & 63, w = t >> 6;
    const int i = b * 1000 + t;

    const int v = (t < 1000) ? deg[i] : 0;
    int incl = v;
    #pragma unroll
    for (int d = 1; d < 64; d <<= 1) {
        const int o = __shfl_up(incl, d);
        if (lane >= d) incl += o;
    }
    if (lane == 63) wsum[w] = incl;
    __syncthreads();
    int wbase = 0;
    for (int k = 0; k < w; ++k) wbase += wsum[k];
    const int excl = wbase + incl - v;

    if (t == 0) {
        int tot = 0;
        #pragma unroll
        for (int k = 0; k < 16; ++k) tot += wsum[k];
        __hip_atomic_store(&bsum[b], tot, __ATOMIC_RELEASE, __HIP_MEMORY_SCOPE_AGENT);
        __hip_atomic_fetch_add(donecnt, 1, __ATOMIC_RELEASE, __HIP_MEMORY_SCOPE_AGENT);
        while (__hip_atomic_load(donecnt, __ATOMIC_ACQUIRE, __HIP_MEMORY_SCOPE_AGENT) < 40)
            __builtin_amdgcn_s_sleep(8);
        int bb = 0;
        for (int k = 0; k < b; ++k)
            bb += __hip_atomic_load(&bsum[k], __ATOMIC_RELAXED, __HIP_MEMORY_SCOPE_AGENT);
        sbb = bb;
    }
    __syncthreads();
    const int bb = sbb;

    if (t < 1000) {
        const int o = excl + bb;
        off[i] = o;
        cur[i] = o;
    }
    if (b == 0 && t == 0) off[NN] = EE;
}

// ---------------------------------------------------------------------------
// K3 k_scatter: bucket src indices by dst (CSR fill)
// ---------------------------------------------------------------------------
__global__ __launch_bounds__(256) void k_scatter(const int* __restrict__ ei,
                                                 int* __restrict__ cur,
                                                 int* __restrict__ esrc)
{
    const int e = blockIdx.x * 256 + threadIdx.x;
    const int src = ei[e];
    const int dst = ei[EE + e];
    const int p = atomicAdd(&cur[dst], 1);
    esrc[p] = src;
}

// ---------------------------------------------------------------------------
// K4 k_gather: pull-mode aggregation. One wave per dst node, 2 cols/lane.
//   v        = (delta[n]-pos[n]) @ Wf1[0:3,:]   (once per node)
//   aggrb[n] = bf16( sum_e leaky(ub[src_e] + v) )
// Unroll 8 for more outstanding gathers.
// ---------------------------------------------------------------------------
__global__ __launch_bounds__(256) void k_gather(
    const int* __restrict__ off, const int* __restrict__ esrc,
    const float* __restrict__ pos, const float* __restrict__ delta,
    const float* __restrict__ Wf1, const unsigned short* __restrict__ ub,
    unsigned short* __restrict__ aggrb)
{
    const int t    = threadIdx.x;
    const int lane = t & 63;
    const int n    = blockIdx.x * 4 + (t >> 6);
    const int c2   = lane * 2;

    const float2 w0 = *(const float2*)(Wf1 + 0 * DD + c2);
    const float2 w1 = *(const float2*)(Wf1 + 1 * DD + c2);
    const float2 w2 = *(const float2*)(Wf1 + 2 * DD + c2);

    const float q0 = delta[n * 3 + 0] - pos[n * 3 + 0];
    const float q1 = delta[n * 3 + 1] - pos[n * 3 + 1];
    const float q2 = delta[n * 3 + 2] - pos[n * 3 + 2];

    const float v0 = q0 * w0.x + q1 * w1.x + q2 * w2.x;
    const float v1 = q0 * w0.y + q1 * w1.y + q2 * w2.y;

    float a0 = 0.f, a1 = 0.f, b0 = 0.f, b1 = 0.f;
    const int beg = off[n], end = off[n + 1];

#define EDGE_ACC(U, A0, A1)                                            \
    {                                                                  \
        const float e0 = __uint_as_float((U) << 16) + v0;              \
        const float e1 = __uint_as_float((U) & 0xffff0000u) + v1;      \
        A0 += leaky1(e0);                                              \
        A1 += leaky1(e1);                                              \
    }

    int j = beg;
    for (; j + 7 < end; j += 8) {
        int s[8];
        unsigned int u[8];
        #pragma unroll
        for (int k = 0; k < 8; ++k) s[k] = esrc[j + k];
        #pragma unroll
        for (int k = 0; k < 8; ++k)
            u[k] = *(const unsigned int*)(ub + (size_t)s[k] * DD + c2);
        #pragma unroll
        for (int k = 0; k < 8; ++k) {
            if (k & 1) { EDGE_ACC(u[k], b0, b1) }
            else       { EDGE_ACC(u[k], a0, a1) }
        }
    }
    for (; j + 3 < end; j += 4) {
        const int s0 = esrc[j];
        const int s1 = esrc[j + 1];
        const int s2 = esrc[j + 2];
        const int s3 = esrc[j + 3];
        const unsigned int u0 = *(const unsigned int*)(ub + (size_t)s0 * DD + c2);
        const unsigned int u1 = *(const unsigned int*)(ub + (size_t)s1 * DD + c2);
        const unsigned int u2 = *(const unsigned int*)(ub + (size_t)s2 * DD + c2);
        const unsigned int u3 = *(const unsigned int*)(ub + (size_t)s3 * DD + c2);
        EDGE_ACC(u0, a0, a1)
        EDGE_ACC(u1, b0, b1)
        EDGE_ACC(u2, a0, a1)
        EDGE_ACC(u3, b0, b1)
    }
    for (; j < end; ++j) {
        const int s0 = esrc[j];
        const unsigned int u0 = *(const unsigned int*)(ub + (size_t)s0 * DD + c2);
        EDGE_ACC(u0, a0, a1)
    }
#undef EDGE_ACC

    a0 += b0; a1 += b1;
    const unsigned int st = ((unsigned int)f2bf(a1) << 16) | (unsigned int)f2bf(a0);
    *(unsigned int*)(aggrb + (size_t)n * DD + c2) = st;
}

// ---------------------------------------------------------------------------
// K5 k_node_out: MFMA node update, LDS-coalesced epilogue.
//   g   = leaky(aggr@Wg1 + bg1);  out = x + g@Wg2 + bg2
// ---------------------------------------------------------------------------
__global__ __launch_bounds__(256) void k_node_out(
    const unsigned short* __restrict__ aggrb, const unsigned short* __restrict__ pk,
    const float* __restrict__ x,
    const float* __restrict__ bg1, const float* __restrict__ bg2,
    float* __restrict__ out)
{
    __shared__ unsigned short gl[64 * 136];
    __shared__ float          ol[64 * 132];
    const int t  = threadIdx.x;
    const int w  = t >> 6, l = t & 63;
    const int lm = l & 15, q = l >> 4;
    const int rowb = blockIdx.x * 64;
    const int row0 = rowb + w * 16;

    const unsigned short* pkg1 = pk + 32768;
    const unsigned short* pkg2 = pk + 49152;

    floatx4 gacc[8];
    #pragma unroll
    for (int ct = 0; ct < 8; ++ct) gacc[ct] = 0.f;

    #pragma unroll
    for (int kc = 0; kc < 4; ++kc) {
        const short8 a = *(const short8*)(aggrb + (size_t)(row0 + lm) * DD + kc * 32 + q * 8);
        #pragma unroll
        for (int ct = 0; ct < 8; ++ct) {
            const short8 b = *(const short8*)(pkg1 + (size_t)((ct * 4 + kc) * 64 + l) * 8);
            gacc[ct] = __builtin_amdgcn_mfma_f32_16x16x32_bf16(a, b, gacc[ct], 0, 0, 0);
        }
    }

    #pragma unroll
    for (int ct = 0; ct < 8; ++ct) {
        const int col = ct * 16 + lm;
        const float b1 = bg1[col];
        #pragma unroll
        for (int r = 0; r < 4; ++r)
            gl[(w * 16 + q * 4 + r) * 136 + col] = f2bf(leaky1(gacc[ct][r] + b1));
    }
    __syncthreads();

    floatx4 oacc[8];
    #pragma unroll
    for (int ct = 0; ct < 8; ++ct) oacc[ct] = 0.f;

    #pragma unroll
    for (int kc = 0; kc < 4; ++kc) {
        const short8 a = *(const short8*)(gl + (size_t)(w * 16 + lm) * 136 + kc * 32 + q * 8);
        #pragma unroll
        for (int ct = 0; ct < 8; ++ct) {
            const short8 b = *(const short8*)(pkg2 + (size_t)((ct * 4 + kc) * 64 + l) * 8);
            oacc[ct] = __builtin_amdgcn_mfma_f32_16x16x32_bf16(a, b, oacc[ct], 0, 0, 0);
        }
    }

    __syncthreads();
    #pragma unroll
    for (int ct = 0; ct < 8; ++ct) {
        const int col = ct * 16 + lm;
        #pragma unroll
        for (int r = 0; r < 4; ++r)
            ol[(w * 16 + q * 4 + r) * 132 + col] = oacc[ct][r];
    }
    __syncthreads();

    #pragma unroll
    for (int k = 0; k < 8; ++k) {
        const int idx = t + k * 256;
        const int row = idx >> 5;
        const int c4  = (idx & 31) * 4;
        const float4 ov = *(const float4*)(ol + row * 132 + c4);
        const float4 bv = *(const float4*)(bg2 + c4);
        const size_t o  = (size_t)(rowb + row) * DD + c4;
        const float4 xv = *(const float4*)(x + o);
        float4 rv;
        rv.x = xv.x + ov.x + bv.x;
        rv.y = xv.y + ov.y + bv.y;
        rv.z = xv.z + ov.z + bv.z;
        rv.w = xv.w + ov.w + bv.w;
        *(float4*)(out + o) = rv;
    }
}

// ---------------------------------------------------------------------------
extern "C" void kernel_launch(void* const* d_in, const int* in_sizes, int n_in,
                              void* d_out, int out_size, void* d_ws, size_t ws_size,
                              hipStream_t stream)
{
    const float* x   = (const float*)d_in[0];
    const float* pos = (const float*)d_in[1];
    const int*   ei  = (const int*)d_in[2];
    const float* Wh1 = (const float*)d_in[3];
    const float* bh1 = (const float*)d_in[4];
    const float* Wh2 = (const float*)d_in[5];
    const float* bh2 = (const float*)d_in[6];
    const float* Wf1 = (const float*)d_in[7];
    const float* bf1 = (const float*)d_in[8];
    const float* Wg1 = (const float*)d_in[9];
    const float* bg1 = (const float*)d_in[10];
    const float* Wg2 = (const float*)d_in[11];
    const float* bg2 = (const float*)d_in[12];
    float* out = (float*)d_out;

    unsigned short* ub    = (unsigned short*)d_ws;          // NN*DD bf16
    unsigned short* aggrb = ub + (size_t)NN * DD;           // NN*DD bf16
    unsigned short* pk    = aggrb + (size_t)NN * DD;        // 4*16384 bf16
    float* delta   = (float*)(pk + 65536);                  // NN*3
    int*   deg     = (int*)(delta + (size_t)NN * 3);        // NN
    int*   off     = deg + NN;                              // NN+4
    int*   cur     = off + NN + 4;                          // NN
    int*   esrc    = cur + NN;                              // EE
    int*   bsum    = esrc + EE;                             // 40
    int*   donecnt = bsum + 40;                             // 1

    k_init<<<160, 256, 0, stream>>>(Wh1, Wf1, Wg1, Wg2, deg, donecnt, pk);
    k_node_pre<<<1250, 256, 0, stream>>>(x, ei, pk, pos, Wf1, bh1, Wh2, bh2,
                                         bf1, deg, ub, delta);
    k_scan<<<40, 1024, 0, stream>>>(deg, off, cur, bsum, donecnt);
    k_scatter<<<EE / 256, 256, 0, stream>>>(ei, cur, esrc);
    k_gather<<<NN / 4, 256, 0, stream>>>(off, esrc, pos, delta, Wf1, ub, aggrb);
    k_node_out<<<NN / 64, 256, 0, stream>>>(aggrb, pk, x, bg1, bg2, out);
}